// Round 9
// baseline (520.406 us; speedup 1.0000x reference)
//
#include <hip/hip_runtime.h>

#define HH 50
#define TT 1024
#define BT 4             // batch tile per block (quarter of MFMA M)
#define NB (2048 / BT)   // 512 blocks -> 2 per CU (cross-block latency hiding)
#define XSTF 1028        // x LDS row stride (floats; 16B-aligned rows, odd bank phase)
#define HST 72           // h LDS row stride (f16 elems)

typedef _Float16 half8 __attribute__((ext_vector_type(8)));
typedef float f32x4 __attribute__((ext_vector_type(4)));

union H8 { half8 v; _Float16 h[8]; unsigned short u[8]; unsigned int i[4]; };

__device__ __forceinline__ float rcp_f(float x) { return __builtin_amdgcn_rcpf(x); }

#if __has_builtin(__builtin_amdgcn_exp2f)
__device__ __forceinline__ float exp2_f(float x) { return __builtin_amdgcn_exp2f(x); }
#else
__device__ __forceinline__ float exp2_f(float x) { return __expf(0.6931471805599453f * x); }
#endif

#define L2E   1.4426950408889634f
#define L2E2  2.8853900817779268f

__device__ __forceinline__ float sigm_n(float a) {   // sigmoid(x), a = -x*log2e
    return rcp_f(1.0f + exp2_f(a));
}
__device__ __forceinline__ float tanh_p(float a) {   // tanh(x), a = 2x*log2e
    return __builtin_fmaf(-2.0f, rcp_f(1.0f + exp2_f(a)), 1.0f);
}
__device__ __forceinline__ unsigned short f2h(float f) {
    return __builtin_bit_cast(unsigned short, (_Float16)f);
}

__global__ __launch_bounds__(256) void lstm_mfma_kernel(
    const float* __restrict__ x,
    const float* __restrict__ wih1, const float* __restrict__ whh1,
    const float* __restrict__ bih1, const float* __restrict__ bhh1,
    const float* __restrict__ wih2,
    const float* __restrict__ bih2, const float* __restrict__ bhh2,
    const float* __restrict__ fcw,  const float* __restrict__ fcb,
    float* __restrict__ out)
{
    __shared__ float xs[BT * XSTF];                          // 16.4 KB (whole sequence)
    __shared__ __align__(16) unsigned short hb[2][16 * HST]; // 4.6 KB (rows 4-15 stay 0)
    __shared__ float h2s[BT * 52];                           // 0.8 KB

    const int tid  = threadIdx.x;
    const int wv   = tid >> 6;        // 0..3 = j-slice
    const int js   = wv;
    const int lane = tid & 63;
    const int l16  = lane & 15;
    const int quad = lane >> 4;
    const int j    = js * 16 + l16;   // padded gate sub-index 0..63
    const bool jv  = (j < HH);
    const bool q2  = (quad == 2);
    const int b0   = blockIdx.x * BT;
    // 1 cell per lane: lane (quad,l16) of wave js owns (batch=quad, j).
    // All valid D values live in quad-0 lanes (rows 0..3 = quad0 regs 0..3).
    // Fan-out acc[G][quad] @ lane l16 -> lane (quad,l16) via permlane tree (no DS ops).

    // ---- persistent per-lane weights: Whh B-frags (f16, gate-folded scale) ----
    // K layout: k=0..49 Whh; k=50 <- Wih (x slot); k=51 <- bias_hi; k=52 <- bias_lo
    H8 bw[4][2];
    #pragma unroll
    for (int t4 = 0; t4 < 4; ++t4) {
        const float sc = (t4 == 2) ? L2E2 : -L2E;
        const int row = t4 * HH + j;
        #pragma unroll
        for (int kk = 0; kk < 2; ++kk)
            #pragma unroll
            for (int e = 0; e < 8; ++e) {
                const int k = kk * 32 + quad * 8 + e;
                const float v = (jv && k < HH) ? whh1[row * HH + k] * sc : 0.0f;
                bw[t4][kk].h[e] = (_Float16)v;
            }
        if (q2) {
            const float bsc = jv ? (bih1[row] + bhh1[row]) * sc : 0.0f;
            const _Float16 bhi = (_Float16)bsc;
            bw[t4][1].h[2] = (_Float16)(jv ? wih1[row] * sc : 0.0f); // k=50
            bw[t4][1].h[3] = bhi;                                    // k=51
            bw[t4][1].h[4] = (_Float16)(bsc - (float)bhi);           // k=52
        }
    }

    // zero h buffers with 1.0 planted at A-slots k=51,52 (race-free single pass)
    for (int i = tid; i < 2 * 16 * HST; i += 256) {
        const int col = i % HST;
        ((unsigned short*)hb)[i] = (col == 51 || col == 52) ? 0x3c00 : 0;
    }

    // stage the ENTIRE x sequence for this block's 4 batches (4 float4 / thread)
    for (int i = tid; i < BT * (TT / 4); i += 256) {
        const int r = i >> 8, c4 = i & 255;
        const float4 q = ((const float4*)x)[((b0 + r) * TT) / 4 + c4];
        *(float4*)&xs[r * XSTF + c4 * 4] = q;
    }
    // ZERO the row pads (cols 1024..1027): the last STEP prefetches xs[..+1024].
    // Round-8 NaN root cause: this pad was uninitialized LDS (stale bits -> NaN
    // -> f16 x-slot -> Inf*0 in LSTM2 MFMA -> all outputs NaN).
    if (tid < BT * 4) xs[(tid >> 2) * XSTF + 1024 + (tid & 3)] = 0.0f;
    __syncthreads();

    const bool xw = (wv == 0) && (lane < BT);   // x-slot writer lanes (row = lane)
    if (xw) hb[0][lane * HST + 50] = f2h(xs[lane * XSTF]);   // x(0)
    __syncthreads();

    float c = 0.f;                       // one cell per lane
    const f32x4 kZ = {0.f, 0.f, 0.f, 0.f};

    // fused cell: 7 trans (5 exp2 + 2 rcp)
    auto cell = [&](float ai, float af, float ag, float ao, float& cc) -> unsigned short {
        const float Ei = exp2_f(ai), Ef = exp2_f(af), Eg = exp2_f(ag), Eo = exp2_f(ao);
        const float pf  = 1.0f + Ef;
        const float P   = (1.0f + Ei) * (1.0f + Eg);
        const float den = pf * P;
        const float num = __builtin_fmaf(cc, P, (Eg - 1.0f) * pf);
        cc = num * rcp_f(den);
        const float ac = fminf(cc * L2E2, 80.0f);
        const float Ec = exp2_f(ac);
        const float h  = (Ec - 1.0f) * rcp_f((1.0f + Eo) * (1.0f + Ec));
        return f2h(h);
    };

    // permlane fan-out: P[lane(quad,i)] = acc[G][quad] from lane i (quad0).
    //   permlane16_swap: vdst rows{1,3} <-> vsrc rows{0,2}  (row = 16 lanes, index-aligned)
    //   permlane32_swap: vdst rows{2,3} <-> vsrc rows{0,1}
#define REDIST(G, PG)                                                          \
    {                                                                          \
        float xx0 = acc[G][0], xx1 = acc[G][1];                                \
        float yy0 = acc[G][2], yy1 = acc[G][3];                                \
        asm("v_permlane16_swap_b32 %0, %1" : "+v"(xx0), "+v"(xx1));            \
        asm("v_permlane16_swap_b32 %0, %1" : "+v"(yy0), "+v"(yy1));            \
        asm("v_permlane32_swap_b32 %0, %1" : "+v"(xx0), "+v"(yy0));            \
        PG = xx0;                                                              \
    }

#define STEP(T, CUR, NXT)                                                      \
    {                                                                          \
        H8 a0, a1;                                                             \
        a0.v = *(const half8*)&(CUR)[l16 * HST + quad * 8];                    \
        a1.v = *(const half8*)&(CUR)[l16 * HST + 32 + quad * 8];               \
        float xnext = 0.0f;                                                    \
        if (xw) xnext = xs[lane * XSTF + (T) + 1];                             \
        f32x4 acc[4];                                                          \
        _Pragma("unroll")                                                      \
        for (int t4 = 0; t4 < 4; ++t4) {                                       \
            acc[t4] = __builtin_amdgcn_mfma_f32_16x16x32_f16(a0.v, bw[t4][0].v, kZ, 0, 0, 0);       \
            acc[t4] = __builtin_amdgcn_mfma_f32_16x16x32_f16(a1.v, bw[t4][1].v, acc[t4], 0, 0, 0);  \
        }                                                                      \
        float p0, p1, p2, p3;                                                  \
        REDIST(0, p0) REDIST(1, p1) REDIST(2, p2) REDIST(3, p3)                \
        const unsigned short hv = cell(p0, p1, p2, p3, c);                     \
        if (jv) (NXT)[quad * HST + j] = hv;  /* j>=50 must not clobber k-slots */ \
        if (xw) (NXT)[lane * HST + 50] = f2h(xnext);                           \
        __syncthreads();                                                       \
    }

    for (int t = 0; t < TT; t += 2) {
        STEP(t,     hb[0], hb[1]);
        STEP(t + 1, hb[1], hb[0]);
    }
#undef STEP
#undef REDIST
    unsigned short* cur = hb[0];   // final h1 (rows 0-3)

    // ---- LSTM2: one cell step from zero state, input = h1 ----
    {
        H8 bw2[4][2];
        float b2[4];
        #pragma unroll
        for (int t4 = 0; t4 < 4; ++t4) {
            const float sc = (t4 == 2) ? L2E2 : -L2E;
            const int row = t4 * HH + j;
            #pragma unroll
            for (int kk = 0; kk < 2; ++kk)
                #pragma unroll
                for (int e = 0; e < 8; ++e) {
                    const int k = kk * 32 + quad * 8 + e;
                    const float v = (jv && k < HH) ? wih2[row * HH + k] * sc : 0.0f;
                    bw2[t4][kk].h[e] = (_Float16)v;
                }
            b2[t4] = jv ? (bih2[row] + bhh2[row]) * sc : 0.0f;
        }
        H8 a0, a1;   // rows 4-15 zero; planted 1.0 & x-slot hit k=50..52 where bw2=0
        a0.v = *(const half8*)&cur[l16 * HST + quad * 8];
        a1.v = *(const half8*)&cur[l16 * HST + 32 + quad * 8];
        f32x4 acc2[4];
        #pragma unroll
        for (int t4 = 0; t4 < 4; ++t4) {
            const f32x4 cb = {b2[t4], b2[t4], b2[t4], b2[t4]};
            acc2[t4] = __builtin_amdgcn_mfma_f32_16x16x32_f16(a0.v, bw2[t4][0].v, cb, 0, 0, 0);
            acc2[t4] = __builtin_amdgcn_mfma_f32_16x16x32_f16(a1.v, bw2[t4][1].v, acc2[t4], 0, 0, 0);
        }
        #pragma unroll
        for (int r = 0; r < 4; ++r) {
            const int b = quad * 4 + r;          // valid rows 0..3 (quad 0)
            const float ig = sigm_n(acc2[0][r]);
            const float gg = tanh_p(acc2[2][r]);
            const float og = sigm_n(acc2[3][r]);
            const float cc = ig * gg;            // f*c0 term vanishes (c0 = 0)
            const float h2 = og * tanh_p(cc * L2E2);
            if (b < BT && jv) h2s[b * 52 + j] = h2;
        }
    }
    __syncthreads();

    // ---- FC: out[b] = h2[b] . fcW + fcb  (4 batches x 16 lanes) ----
    if (tid < BT * 16) {
        const int b = tid >> 4, l = tid & 15;
        float p = 0.f;
        for (int jj = l; jj < HH; jj += 16)
            p = __builtin_fmaf(h2s[b * 52 + jj], fcw[jj], p);
        #pragma unroll
        for (int off = 8; off > 0; off >>= 1) p += __shfl_xor(p, off, 16);
        if (l == 0) out[b0 + b] = p + fcb[0];
    }
}

extern "C" void kernel_launch(void* const* d_in, const int* in_sizes, int n_in,
                              void* d_out, int out_size, void* d_ws, size_t ws_size,
                              hipStream_t stream) {
    lstm_mfma_kernel<<<NB, 256, 0, stream>>>(
        (const float*)d_in[0],                         // x
        (const float*)d_in[1], (const float*)d_in[2],  // lstm1 Wih, Whh
        (const float*)d_in[3], (const float*)d_in[4],  // lstm1 bih, bhh
        (const float*)d_in[5],                         // lstm2 Wih
        (const float*)d_in[7], (const float*)d_in[8],  // lstm2 bih, bhh
        (const float*)d_in[9], (const float*)d_in[10], // fc W, b
        (float*)d_out);
}

// Round 10
// 432.296 us; speedup vs baseline: 1.2038x; 1.2038x over previous
//
#include <hip/hip_runtime.h>

#define HH 50
#define TT 1024
#define BT 8             // batch tile per block (half an MFMA M)
#define NB (2048 / BT)   // 256 blocks -> 1 per CU, all CUs active
#define XSTF 1028        // x LDS row stride (floats; pad cols 1024..1027 zeroed)
#define HST 72           // h LDS row stride (f16 elems)

typedef _Float16 half8 __attribute__((ext_vector_type(8)));
typedef float f32x4 __attribute__((ext_vector_type(4)));

union H8 { half8 v; _Float16 h[8]; unsigned short u[8]; unsigned int i[4]; };

__device__ __forceinline__ float rcp_f(float x) { return __builtin_amdgcn_rcpf(x); }

#if __has_builtin(__builtin_amdgcn_exp2f)
__device__ __forceinline__ float exp2_f(float x) { return __builtin_amdgcn_exp2f(x); }
#else
__device__ __forceinline__ float exp2_f(float x) { return __expf(0.6931471805599453f * x); }
#endif

#define L2E   1.4426950408889634f
#define L2E2  2.8853900817779268f

__device__ __forceinline__ float sigm_n(float a) {   // sigmoid(x), a = -x*log2e
    return rcp_f(1.0f + exp2_f(a));
}
__device__ __forceinline__ float tanh_p(float a) {   // tanh(x), a = 2x*log2e
    return __builtin_fmaf(-2.0f, rcp_f(1.0f + exp2_f(a)), 1.0f);
}
__device__ __forceinline__ unsigned short f2h(float f) {
    return __builtin_bit_cast(unsigned short, (_Float16)f);
}

__global__ __launch_bounds__(256) void lstm_mfma_kernel(
    const float* __restrict__ x,
    const float* __restrict__ wih1, const float* __restrict__ whh1,
    const float* __restrict__ bih1, const float* __restrict__ bhh1,
    const float* __restrict__ wih2,
    const float* __restrict__ bih2, const float* __restrict__ bhh2,
    const float* __restrict__ fcw,  const float* __restrict__ fcb,
    float* __restrict__ out)
{
    __shared__ float xs[BT * XSTF];                          // 32.9 KB (whole sequence)
    __shared__ __align__(16) unsigned short hb[2][16 * HST]; // 4.6 KB (rows 8-15 stay 0)
    __shared__ float h2s[BT * 52];                           // 1.7 KB

    const int tid  = threadIdx.x;
    const int wv   = tid >> 6;        // 0..3 = j-slice
    const int js   = wv;
    const int lane = tid & 63;
    const int l16  = lane & 15;
    const int quad = lane >> 4;
    const int j    = js * 16 + l16;   // padded gate sub-index 0..63
    const bool jv  = (j < HH);
    const bool q2  = (quad == 2);
    const int b0   = blockIdx.x * BT;
    // 2 cells/lane ownership (round-7 mapping): lane (quad,l16) owns batches
    // bm0, bm0+1 with bm0 = q0:0, q1:4, q2:2, q3:6.  acc[G][r] holds batch
    // quad*4+r (valid rows 0..7 live in quads 0,1).  Redistribution via
    // v_permlane32_swap (semantics verified by round-9 pass: vdst.lo kept,
    // vdst.hi <- vsrc.lo):  P0=acc[0]; swap(P0,acc[2]) -> lo lanes keep own
    // regs (b0,b1 / b4,b5), hi lanes get q0/q1's regs 2,3 (b2,b3 / b6,b7).
    const int  bm0   = ((quad & 1) << 2) + ((quad >> 1) << 1);   // first owned row

    // ---- persistent per-lane weights: Whh B-frags (f16, gate-folded scale) ----
    // K layout: k=0..49 Whh; k=50 <- Wih (x slot); k=51 <- bias_hi; k=52 <- bias_lo
    H8 bw[4][2];
    #pragma unroll
    for (int t4 = 0; t4 < 4; ++t4) {
        const float sc = (t4 == 2) ? L2E2 : -L2E;
        const int row = t4 * HH + j;
        #pragma unroll
        for (int kk = 0; kk < 2; ++kk)
            #pragma unroll
            for (int e = 0; e < 8; ++e) {
                const int k = kk * 32 + quad * 8 + e;
                const float v = (jv && k < HH) ? whh1[row * HH + k] * sc : 0.0f;
                bw[t4][kk].h[e] = (_Float16)v;
            }
        if (q2) {
            const float bsc = jv ? (bih1[row] + bhh1[row]) * sc : 0.0f;
            const _Float16 bhi = (_Float16)bsc;
            bw[t4][1].h[2] = (_Float16)(jv ? wih1[row] * sc : 0.0f); // k=50
            bw[t4][1].h[3] = bhi;                                    // k=51
            bw[t4][1].h[4] = (_Float16)(bsc - (float)bhi);           // k=52
        }
    }

    // zero h buffers with 1.0 planted at A-slots k=51,52 (race-free single pass)
    for (int i = tid; i < 2 * 16 * HST; i += 256) {
        const int col = i % HST;
        ((unsigned short*)hb)[i] = (col == 51 || col == 52) ? 0x3c00 : 0;
    }

    // stage the ENTIRE x sequence for this block's 8 batches (8 float4 / thread)
    for (int i = tid; i < BT * (TT / 4); i += 256) {
        const int r = i >> 8, c4 = i & 255;
        const float4 q = ((const float4*)x)[((b0 + r) * TT) / 4 + c4];
        *(float4*)&xs[r * XSTF + c4 * 4] = q;
    }
    // zero the row pads (cols 1024..1027): last STEP prefetches xs[..+1024]
    // (round-8 lesson: uninitialized pad -> NaN through the k=50 A-slot)
    if (tid < BT * 4) xs[(tid >> 2) * XSTF + 1024 + (tid & 3)] = 0.0f;
    __syncthreads();

    const bool xw = (wv == 0) && (lane < BT);   // x-slot writer lanes (row = lane)
    if (xw) hb[0][lane * HST + 50] = f2h(xs[lane * XSTF]);   // x(0)
    __syncthreads();

    float c0 = 0.f, c1 = 0.f;            // two cells per lane (rows bm0, bm0+1)
    const f32x4 kZ = {0.f, 0.f, 0.f, 0.f};

    // fused cell: 7 trans (5 exp2 + 2 rcp)
    auto cell = [&](float ai, float af, float ag, float ao, float& cc) -> unsigned short {
        const float Ei = exp2_f(ai), Ef = exp2_f(af), Eg = exp2_f(ag), Eo = exp2_f(ao);
        const float pf  = 1.0f + Ef;
        const float P   = (1.0f + Ei) * (1.0f + Eg);
        const float den = pf * P;
        const float num = __builtin_fmaf(cc, P, (Eg - 1.0f) * pf);
        cc = num * rcp_f(den);
        const float ac = fminf(cc * L2E2, 80.0f);
        const float Ec = exp2_f(ac);
        const float h  = (Ec - 1.0f) * rcp_f((1.0f + Eo) * (1.0f + Ec));
        return f2h(h);
    };

    // redistribution: 2 permlane32_swap per gate, no cndmask, no DS ops
#define REDIST(G, P0, P1)                                                      \
    {                                                                          \
        float a_ = acc[G][0], b_ = acc[G][1];                                  \
        float c_ = acc[G][2], d_ = acc[G][3];                                  \
        asm("v_permlane32_swap_b32 %0, %1" : "+v"(a_), "+v"(c_));              \
        asm("v_permlane32_swap_b32 %0, %1" : "+v"(b_), "+v"(d_));              \
        P0 = a_;                                                               \
        P1 = b_;                                                               \
    }

#define STEP(T, CUR, NXT)                                                      \
    {                                                                          \
        H8 a0, a1;                                                             \
        a0.v = *(const half8*)&(CUR)[l16 * HST + quad * 8];                    \
        a1.v = *(const half8*)&(CUR)[l16 * HST + 32 + quad * 8];               \
        float xnext = 0.0f;                                                    \
        if (xw) xnext = xs[lane * XSTF + (T) + 1];                             \
        f32x4 acc[4];                                                          \
        _Pragma("unroll")                                                      \
        for (int t4 = 0; t4 < 4; ++t4) {                                       \
            acc[t4] = __builtin_amdgcn_mfma_f32_16x16x32_f16(a0.v, bw[t4][0].v, kZ, 0, 0, 0);       \
            acc[t4] = __builtin_amdgcn_mfma_f32_16x16x32_f16(a1.v, bw[t4][1].v, acc[t4], 0, 0, 0);  \
        }                                                                      \
        float pi0, pi1, pf0, pf1, pg0, pg1, po0, po1;                          \
        REDIST(0, pi0, pi1) REDIST(1, pf0, pf1)                                \
        REDIST(2, pg0, pg1) REDIST(3, po0, po1)                                \
        const unsigned short h0 = cell(pi0, pf0, pg0, po0, c0);                \
        const unsigned short h1 = cell(pi1, pf1, pg1, po1, c1);                \
        if (jv) {   /* j>=50 lanes must not clobber the planted k-slots */     \
            (NXT)[bm0 * HST + j]       = h0;                                   \
            (NXT)[(bm0 + 1) * HST + j] = h1;                                   \
        }                                                                      \
        if (xw) (NXT)[lane * HST + 50] = f2h(xnext);                           \
        __syncthreads();                                                       \
    }

    for (int t = 0; t < TT; t += 2) {
        STEP(t,     hb[0], hb[1]);
        STEP(t + 1, hb[1], hb[0]);
    }
#undef STEP
#undef REDIST
    unsigned short* cur = hb[0];   // final h1 (rows 0-7)

    // ---- LSTM2: one cell step from zero state, input = h1 ----
    {
        H8 bw2[4][2];
        float b2[4];
        #pragma unroll
        for (int t4 = 0; t4 < 4; ++t4) {
            const float sc = (t4 == 2) ? L2E2 : -L2E;
            const int row = t4 * HH + j;
            #pragma unroll
            for (int kk = 0; kk < 2; ++kk)
                #pragma unroll
                for (int e = 0; e < 8; ++e) {
                    const int k = kk * 32 + quad * 8 + e;
                    const float v = (jv && k < HH) ? wih2[row * HH + k] * sc : 0.0f;
                    bw2[t4][kk].h[e] = (_Float16)v;
                }
            b2[t4] = jv ? (bih2[row] + bhh2[row]) * sc : 0.0f;
        }
        H8 a0, a1;   // rows 8-15 zero; planted 1.0 & x-slot hit k=50..52 where bw2=0
        a0.v = *(const half8*)&cur[l16 * HST + quad * 8];
        a1.v = *(const half8*)&cur[l16 * HST + 32 + quad * 8];
        f32x4 acc2[4];
        #pragma unroll
        for (int t4 = 0; t4 < 4; ++t4) {
            const f32x4 cb = {b2[t4], b2[t4], b2[t4], b2[t4]};
            acc2[t4] = __builtin_amdgcn_mfma_f32_16x16x32_f16(a0.v, bw2[t4][0].v, cb, 0, 0, 0);
            acc2[t4] = __builtin_amdgcn_mfma_f32_16x16x32_f16(a1.v, bw2[t4][1].v, acc2[t4], 0, 0, 0);
        }
        #pragma unroll
        for (int r = 0; r < 4; ++r) {
            const int b = quad * 4 + r;          // valid rows 0..7 (quads 0,1)
            const float ig = sigm_n(acc2[0][r]);
            const float gg = tanh_p(acc2[2][r]);
            const float og = sigm_n(acc2[3][r]);
            const float cc = ig * gg;            // f*c0 term vanishes (c0 = 0)
            const float h2 = og * tanh_p(cc * L2E2);
            if (b < BT && jv) h2s[b * 52 + j] = h2;
        }
    }
    __syncthreads();

    // ---- FC: out[b] = h2[b] . fcW + fcb  (8 batches x 16 lanes) ----
    if (tid < BT * 16) {
        const int b = tid >> 4, l = tid & 15;
        float p = 0.f;
        for (int jj = l; jj < HH; jj += 16)
            p = __builtin_fmaf(h2s[b * 52 + jj], fcw[jj], p);
        #pragma unroll
        for (int off = 8; off > 0; off >>= 1) p += __shfl_xor(p, off, 16);
        if (l == 0) out[b0 + b] = p + fcb[0];
    }
}

extern "C" void kernel_launch(void* const* d_in, const int* in_sizes, int n_in,
                              void* d_out, int out_size, void* d_ws, size_t ws_size,
                              hipStream_t stream) {
    lstm_mfma_kernel<<<NB, 256, 0, stream>>>(
        (const float*)d_in[0],                         // x
        (const float*)d_in[1], (const float*)d_in[2],  // lstm1 Wih, Whh
        (const float*)d_in[3], (const float*)d_in[4],  // lstm1 bih, bhh
        (const float*)d_in[5],                         // lstm2 Wih
        (const float*)d_in[7], (const float*)d_in[8],  // lstm2 bih, bhh
        (const float*)d_in[9], (const float*)d_in[10], // fc W, b
        (float*)d_out);
}